// Round 17
// baseline (238.665 us; speedup 1.0000x reference)
//
#include <hip/hip_runtime.h>
#include <hip/hip_bf16.h>

// RGCN gather-mm, etype-sorted edges.
// out[v][n] = sum_{e: dst[e]=v} sum_k feat[src[e]][k] * W[etype[e]][k][n]
//
// R28: scatter occupancy fix. R27 (235.0us) falsified the dispatch-gap
// model (removing a boundary = ~2us). Corrected budget: proj 65 + prep 3 +
// gaps ~6 => scatter+reduce ~160us, both under the 65.2 top-5 cutoff.
// reduce ~= its 237MB traffic bound (~60us). scatter: 27MB traffic (~7us
// bound) but ran as 196 x 1024-thr blocks -- FEWER BLOCKS THAN CUs, each a
// serial 3-barrier chain => latency-bound ~45-60us (R24 accounting: ~47).
// Fix: 512thr x 2048 edges/block -> 782 blocks (~3/CU), per-phase serial
// length /4, barrier overlap across co-resident blocks. All else = R27
// (prep fused, proj R25 grid.y=2 + usedb guard, bucket_reduce R23 sort).
// NEVER: LDS atomic accumulators (R22: ds_add_f32 RMW = 687us).
// Fallback: R4 atomic kernel (433us, known-good).

#define NTHREADS 256
#define TM 64
#define CH 2560          // bucket_reduce LDS chunk (items); avg bucket 2046
#define SC_THREADS 512
#define SC_EPB 2048      // edges per scatter block (512 thr x 4)

typedef __attribute__((ext_vector_type(8))) __bf16 bf16x8;
typedef __attribute__((ext_vector_type(4))) float f32x4;

// ---- prep: zero bcnt + usedb, cvt W [R][128][64] fp32 -> [R][64][128] bf16 ----
__global__ __launch_bounds__(256)
void prep_kernel(const float* __restrict__ w, __bf16* __restrict__ wtb, int nw,
                 int* __restrict__ bcnt, int NB,
                 unsigned* __restrict__ usedw, int uw) {
    long idx = (long)blockIdx.x * 256 + threadIdx.x;
    long tot = (long)NB + uw + nw;
    for (long i = idx; i < tot; i += (long)gridDim.x * 256) {
        if (i < NB) {
            bcnt[i] = 0;
        } else if (i < (long)NB + uw) {
            usedw[i - NB] = 0u;
        } else {
            int j = (int)(i - NB - uw);
            int r = j >> 13;
            int rem = j & 8191;
            int k = rem >> 6;
            int n = rem & 63;
            wtb[((size_t)r << 13) + (n << 7) + k] = (__bf16)w[j];
        }
    }
}

// ---- dense projection: HALF the relations per block (grid.y), LDS dbuf,
// ---- raw barriers, used-row-guarded stores (R25, proven 62.6us) ----
__global__ __launch_bounds__(NTHREADS)
void proj_all_kernel(const float* __restrict__ feat, const __bf16* __restrict__ wtb,
                     const unsigned char* __restrict__ usedb,
                     int N, int R, __bf16* __restrict__ projb) {
    __shared__ __bf16 Wt[2][64 * 136];
    __shared__ unsigned used_l[16 * 32];   // rpb<=16 x 128 bytes, as u32

    int t = threadIdx.x;
    int wave = t >> 6, lane = t & 63;
    int q = lane >> 4, m = lane & 15;
    long blk0 = (long)blockIdx.x * 128;
    long node0 = blk0 + wave * 32;

    int rpb = (R + 1) >> 1;                 // relations per block
    int r0 = blockIdx.y * rpb;
    int r1 = r0 + rpb; if (r1 > R) r1 = R;
    int nr = r1 - r0;
    if (nr <= 0) return;

    // preload used bytes for this block's 128 nodes x [r0,r1) relations
    for (int c = t; c < nr * 32; c += NTHREADS) {
        int rr = c >> 5, i = c & 31;
        used_l[rr * 32 + i] = *(const unsigned*)(usedb + (size_t)(r0 + rr) * N + blk0 + i * 4);
    }

    // A fragments: fp32 feat -> bf16, loaded once for this block's relations.
    bf16x8 a[2][4];
    #pragma unroll
    for (int mt = 0; mt < 2; mt++) {
        long nd = node0 + mt * 16 + m;
        if (nd > N - 1) nd = N - 1;
        const float* arow = feat + nd * 128;
        #pragma unroll
        for (int ks = 0; ks < 4; ks++) {
            float4 fa = *(const float4*)(arow + ks * 32 + q * 8);
            float4 fb = *(const float4*)(arow + ks * 32 + q * 8 + 4);
            bf16x8 v;
            v[0] = (__bf16)fa.x; v[1] = (__bf16)fa.y; v[2] = (__bf16)fa.z; v[3] = (__bf16)fa.w;
            v[4] = (__bf16)fb.x; v[5] = (__bf16)fb.y; v[6] = (__bf16)fb.z; v[7] = (__bf16)fb.w;
            a[mt][ks] = v;
        }
    }

    // stage r=r0 into buffer 0
    {
        const __bf16* wg = wtb + ((size_t)r0 << 13);
        #pragma unroll
        for (int i = 0; i < 4; i++) {
            int c = t + i * 256;
            int n = c >> 4, kc = c & 15;
            *(bf16x8*)(&Wt[0][n * 136 + kc * 8]) = *(const bf16x8*)(wg + n * 128 + kc * 8);
        }
    }
    asm volatile("s_waitcnt lgkmcnt(0)" ::: "memory");
    __builtin_amdgcn_s_barrier();
    __builtin_amdgcn_sched_barrier(0);

    for (int ri = 0; ri < nr; ri++) {
        int r = r0 + ri;
        int cur = ri & 1, nxt = cur ^ 1;
        bool pf = (ri + 1 < nr);

        // T14 async-STAGE: issue next-relation W loads now; write to LDS late.
        bf16x8 wreg[4];
        if (pf) {
            const __bf16* wg = wtb + ((size_t)(r + 1) << 13);
            #pragma unroll
            for (int i = 0; i < 4; i++) {
                int c = t + i * 256;
                int n = c >> 4, kc = c & 15;
                wreg[i] = *(const bf16x8*)(wg + n * 128 + kc * 8);
            }
        }

        f32x4 acc[2][4] = {};
        #pragma unroll
        for (int ks = 0; ks < 4; ks++) {
            bf16x8 b0 = *(const bf16x8*)(&Wt[cur][(0 * 16 + m) * 136 + ks * 32 + q * 8]);
            bf16x8 b1 = *(const bf16x8*)(&Wt[cur][(1 * 16 + m) * 136 + ks * 32 + q * 8]);
            bf16x8 b2 = *(const bf16x8*)(&Wt[cur][(2 * 16 + m) * 136 + ks * 32 + q * 8]);
            bf16x8 b3 = *(const bf16x8*)(&Wt[cur][(3 * 16 + m) * 136 + ks * 32 + q * 8]);
            #pragma unroll
            for (int mt = 0; mt < 2; mt++) {
                acc[mt][0] = __builtin_amdgcn_mfma_f32_16x16x32_bf16(a[mt][ks], b0, acc[mt][0], 0, 0, 0);
                acc[mt][1] = __builtin_amdgcn_mfma_f32_16x16x32_bf16(a[mt][ks], b1, acc[mt][1], 0, 0, 0);
                acc[mt][2] = __builtin_amdgcn_mfma_f32_16x16x32_bf16(a[mt][ks], b2, acc[mt][2], 0, 0, 0);
                acc[mt][3] = __builtin_amdgcn_mfma_f32_16x16x32_bf16(a[mt][ks], b3, acc[mt][3], 0, 0, 0);
            }
        }

        // C/D: col = nt*16+m, node = mt*16+q*4+reg. Permuted c' = m*4+nt.
        // Store only rows some edge will read (usedb guard).
        #pragma unroll
        for (int mt = 0; mt < 2; mt++) {
            unsigned g = used_l[ri * 32 + ((wave * 32 + mt * 16 + q * 4) >> 2)];
            #pragma unroll
            for (int reg = 0; reg < 4; reg++) {
                long nd = node0 + mt * 16 + q * 4 + reg;
                if (nd < N && ((g >> (reg * 8)) & 1)) {
                    union { unsigned long long u; __bf16 h[4]; } pk;
                    pk.h[0] = (__bf16)acc[mt][0][reg];
                    pk.h[1] = (__bf16)acc[mt][1][reg];
                    pk.h[2] = (__bf16)acc[mt][2][reg];
                    pk.h[3] = (__bf16)acc[mt][3][reg];
                    *(unsigned long long*)(projb + ((size_t)r * N + nd) * 64 + m * 4) = pk.u;
                }
            }
        }

        if (pf) {
            #pragma unroll
            for (int i = 0; i < 4; i++) {
                int c = t + i * 256;
                int n = c >> 4, kc = c & 15;
                *(bf16x8*)(&Wt[nxt][n * 136 + kc * 8]) = wreg[i];
            }
            asm volatile("s_waitcnt lgkmcnt(0)" ::: "memory");
            __builtin_amdgcn_s_barrier();
            __builtin_amdgcn_sched_barrier(0);
        }
    }
}

// ---- LDS-binned scatter into FIXED-STRIDE buckets (R28: 512thr/2048 edges,
// ---- 782 blocks ~3/CU; was 196 x 1024thr = latency-bound serial chains) ----
// item = (dst&127)<<24 | (etype*N + src)   [R*N < 2^24 guarded]
// Reserves per-bucket slots via atomicAdd(bcnt) -- no hist/scan needed.
// Also marks usedb[etype*N+src] (idempotent byte store) for proj's guard.
__global__ __launch_bounds__(SC_THREADS)
void bucket_scatter(const int* __restrict__ dst, const int* __restrict__ src,
                    const int* __restrict__ etypes, int E, int N, int NB, int STRIDE,
                    int* __restrict__ bcnt, int* __restrict__ items,
                    unsigned char* __restrict__ usedb) {
    __shared__ int lh[1024], lb[1024];
    int t = threadIdx.x;
    for (int i = t; i < 1024; i += SC_THREADS) lh[i] = 0;
    __syncthreads();
    long base = (long)blockIdx.x * SC_EPB;
    int bs[4], it[4];
    #pragma unroll
    for (int i = 0; i < 4; i++) {
        long e = base + t + SC_THREADS * i;
        if (e < E) {
            int d = dst[e];
            int bkt = d >> 7;
            bs[i] = bkt;
            int pair = etypes[e] * N + src[e];
            it[i] = ((d & 127) << 24) | pair;
            usedb[pair] = 1;
            atomicAdd(&lh[bkt], 1);
        } else bs[i] = -1;
    }
    __syncthreads();
    for (int bb = t; bb < NB; bb += SC_THREADS) {
        int c = lh[bb];
        lb[bb] = c ? atomicAdd(&bcnt[bb], c) : 0;
        lh[bb] = 0;
    }
    __syncthreads();
    #pragma unroll
    for (int i = 0; i < 4; i++) {
        if (bs[i] >= 0) {
            int pos = lb[bs[i]] + atomicAdd(&lh[bs[i]], 1);
            if (pos < STRIDE)
                items[(size_t)bs[i] * STRIDE + pos] = it[i];
        }
    }
}

// ---- fused sort+reduce per bucket (R21/R23 core, fixed-stride input) ----
// Chunked LDS counting sort of the bucket's 24-bit pairs, then gather-
// reduce from LDS: 64 8-lane subs, sub handles dsts {sub, sub+64} with
// register acc; lane c8 owns permuted cols c8*8..c8*8+7 (16B/row gather).
__global__ __launch_bounds__(512)
void bucket_reduce(const int* __restrict__ bcnt, const int* __restrict__ items,
                   int STRIDE, const __bf16* __restrict__ projb, int N,
                   float* __restrict__ out) {
    __shared__ int h[128], sc[128], cur[128];
    __shared__ int its[CH];
    int b = blockIdx.x, t = threadIdx.x;
    int cnt = bcnt[b]; if (cnt > STRIDE) cnt = STRIDE;
    const int* bitems = items + (size_t)b * STRIDE;
    int sub = t >> 3, c8 = t & 7;

    float acc[2][8] = {};

    for (int c0 = 0; c0 < cnt; c0 += CH) {
        int n = cnt - c0; if (n > CH) n = CH;

        if (t < 128) h[t] = 0;
        __syncthreads();

        int my[CH / 512];
        int dl[CH / 512];
        #pragma unroll
        for (int i = 0; i < CH / 512; i++) {
            int k = t + i * 512;
            if (k < n) {
                my[i] = bitems[c0 + k];
                dl[i] = ((unsigned)my[i]) >> 24;
                atomicAdd(&h[dl[i]], 1);
            } else dl[i] = -1;
        }
        __syncthreads();

        if (t < 128) sc[t] = h[t];
        __syncthreads();
        for (int s = 1; s < 128; s <<= 1) {        // inclusive scan
            int add = (t >= s && t < 128) ? sc[t - s] : 0;
            __syncthreads();
            if (t < 128) sc[t] += add;
            __syncthreads();
        }
        if (t < 128) cur[t] = sc[t] - h[t];        // exclusive
        __syncthreads();

        #pragma unroll
        for (int i = 0; i < CH / 512; i++) {
            if (dl[i] >= 0) {
                int pos = atomicAdd(&cur[dl[i]], 1);
                its[pos] = my[i] & 0xFFFFFF;
            }
        }
        __syncthreads();

        // gather-reduce this chunk's sorted runs
        #pragma unroll
        for (int idx = 0; idx < 2; idx++) {
            int d = sub + idx * 64;
            int s = sc[d] - h[d];
            int e = sc[d];
            int k = s;
            for (; k + 1 < e; k += 2) {
                int p0 = its[k], p1 = its[k + 1];
                bf16x8 v0 = *(const bf16x8*)(projb + (size_t)p0 * 64 + c8 * 8);
                bf16x8 v1 = *(const bf16x8*)(projb + (size_t)p1 * 64 + c8 * 8);
                #pragma unroll
                for (int i = 0; i < 8; i++) acc[idx][i] += (float)v0[i] + (float)v1[i];
            }
            if (k < e) {
                int p = its[k];
                bf16x8 v0 = *(const bf16x8*)(projb + (size_t)p * 64 + c8 * 8);
                #pragma unroll
                for (int i = 0; i < 8; i++) acc[idx][i] += (float)v0[i];
            }
        }
        __syncthreads();   // its/h/sc reused next chunk
    }

    // store: v = b*128 + d, lane owns permuted cols c8*8..+7
    #pragma unroll
    for (int idx = 0; idx < 2; idx++) {
        long v = (long)b * 128 + sub + idx * 64;
        if (v < N) {
            float* orow = out + (size_t)v * 64;
            #pragma unroll
            for (int i = 0; i < 8; i++) {
                int cp = c8 * 8 + i;
                orow[(cp & 3) * 16 + (cp >> 2)] = acc[idx][i];
            }
        }
    }
}

// ---- fallback: atomic scatter (R4, known-good 433us; no ws use) ----
__global__ __launch_bounds__(NTHREADS)
void rgcn_atomic(const float* __restrict__ feat, const float* __restrict__ weight,
                 const int* __restrict__ src, const int* __restrict__ dst,
                 const int* __restrict__ etypes, int E,
                 float* __restrict__ out) {
    __shared__ __bf16 Wt[64 * 136];
    int b = blockIdx.x;
    int e0 = b * TM;
    int t = threadIdx.x;
    int wave = t >> 6, lane = t & 63;
    int q = lane >> 4, m = lane & 15;
    int wbase = e0 + wave * 16;
    int last = e0 + TM - 1; if (last > E - 1) last = E - 1;
    int rmin = etypes[e0];
    int rmax = etypes[last];
    int em = wbase + m;
    bool rowok = em < E;
    int ei = rowok ? em : E - 1;
    int my_et = rowok ? etypes[em] : -1;
    const float* arow = feat + (long)src[ei] * 128;
    bf16x8 a[4];
    #pragma unroll
    for (int ks = 0; ks < 4; ks++) {
        float4 fa = *(const float4*)(arow + ks * 32 + q * 8);
        float4 fb = *(const float4*)(arow + ks * 32 + q * 8 + 4);
        bf16x8 v;
        v[0] = (__bf16)fa.x; v[1] = (__bf16)fa.y;
        v[2] = (__bf16)fa.z; v[3] = (__bf16)fa.w;
        v[4] = (__bf16)fb.x; v[5] = (__bf16)fb.y;
        v[6] = (__bf16)fb.z; v[7] = (__bf16)fb.w;
        a[ks] = v;
    }
    f32x4 acc0 = {0.f, 0.f, 0.f, 0.f};
    f32x4 acc1 = {0.f, 0.f, 0.f, 0.f};
    f32x4 acc2 = {0.f, 0.f, 0.f, 0.f};
    f32x4 acc3 = {0.f, 0.f, 0.f, 0.f};
    for (int r = rmin; r <= rmax; ++r) {
        if (r != rmin) __syncthreads();
        const float* wg = weight + (r << 13);
        for (int p = t; p < 4096; p += NTHREADS) {
            int n = p & 63, kh = p >> 6;
            float w0 = wg[(kh * 2) * 64 + n];
            float w1 = wg[(kh * 2 + 1) * 64 + n];
            union { unsigned u; __bf16 h[2]; } pk;
            pk.h[0] = (__bf16)w0; pk.h[1] = (__bf16)w1;
            *(unsigned*)&Wt[n * 136 + kh * 2] = pk.u;
        }
        __syncthreads();
        bool on = (my_et == r);
        #pragma unroll
        for (int ks = 0; ks < 4; ks++) {
            bf16x8 af = a[ks];
            if (!on) {
                #pragma unroll
                for (int j = 0; j < 8; j++) af[j] = (__bf16)0.f;
            }
            bf16x8 b0 = *(const bf16x8*)(&Wt[(0 * 16 + m) * 136 + ks * 32 + q * 8]);
            bf16x8 b1 = *(const bf16x8*)(&Wt[(1 * 16 + m) * 136 + ks * 32 + q * 8]);
            bf16x8 b2 = *(const bf16x8*)(&Wt[(2 * 16 + m) * 136 + ks * 32 + q * 8]);
            bf16x8 b3 = *(const bf16x8*)(&Wt[(3 * 16 + m) * 136 + ks * 32 + q * 8]);
            acc0 = __builtin_amdgcn_mfma_f32_16x16x32_bf16(af, b0, acc0, 0, 0, 0);
            acc1 = __builtin_amdgcn_mfma_f32_16x16x32_bf16(af, b1, acc1, 0, 0, 0);
            acc2 = __builtin_amdgcn_mfma_f32_16x16x32_bf16(af, b2, acc2, 0, 0, 0);
            acc3 = __builtin_amdgcn_mfma_f32_16x16x32_bf16(af, b3, acc3, 0, 0, 0);
        }
    }
    #pragma unroll
    for (int reg = 0; reg < 4; reg++) {
        int er = wbase + q * 4 + reg;
        if (er < E) {
            float* orow = out + (long)dst[er] * 64;
            unsafeAtomicAdd(orow + 0 * 16 + m, acc0[reg]);
            unsafeAtomicAdd(orow + 1 * 16 + m, acc1[reg]);
            unsafeAtomicAdd(orow + 2 * 16 + m, acc2[reg]);
            unsafeAtomicAdd(orow + 3 * 16 + m, acc3[reg]);
        }
    }
}

extern "C" void kernel_launch(void* const* d_in, const int* in_sizes, int n_in,
                              void* d_out, int out_size, void* d_ws, size_t ws_size,
                              hipStream_t stream) {
    const float* feat   = (const float*)d_in[0];
    const float* weight = (const float*)d_in[1];
    const int*   src    = (const int*)d_in[2];
    const int*   dst    = (const int*)d_in[3];
    const int*   etypes = (const int*)d_in[4];
    float* out = (float*)d_out;

    int nfeat = in_sizes[0];
    int nw    = in_sizes[1];
    int E     = in_sizes[2];
    int N     = nfeat / 128;
    int R     = nw >> 13;
    int NB    = (N + 127) >> 7;      // buckets of 128 dsts

    // fixed bucket stride: 2x average, 64-aligned, >=1024
    int avg = (int)(((long)E + NB - 1) / NB);
    int STRIDE = ((avg * 2 + 63) / 64) * 64;
    if (STRIDE < 1024) STRIDE = 1024;

    // ws layout (256B-aligned slabs)
    size_t o = 0;
    auto take = [&](size_t bytes) { size_t r = o; o = (o + bytes + 255) & ~(size_t)255; return r; };
    size_t o_bcnt  = take((size_t)NB * 4);
    size_t o_usedb = take((size_t)R * N);          // used (r,src) byte map
    size_t o_items = take((size_t)NB * STRIDE * 4);
    size_t o_wtb   = take((size_t)nw * 2);
    size_t o_projb = take((size_t)R * N * 64 * 2);
    size_t need = o;

    bool fast = (ws_size >= need) && (NB <= 1024) && ((size_t)R * N < (1u << 24))
                && (R <= 16) && ((N & 3) == 0);

    if (fast) {
        char* ws = (char*)d_ws;
        int* bcnt  = (int*)(ws + o_bcnt);
        unsigned char* usedb = (unsigned char*)(ws + o_usedb);
        int* items = (int*)(ws + o_items);
        __bf16* wtb   = (__bf16*)(ws + o_wtb);
        __bf16* projb = (__bf16*)(ws + o_projb);

        int uw = (int)(((size_t)R * N + 3) >> 2);      // usedb words (slab padded)
        long ptot = (long)NB + uw + nw;
        int pgrid_n = (int)((ptot + 255) / 256);
        if (pgrid_n > 2048) pgrid_n = 2048;            // grid-stride caps the rest

        int cgrid = (int)(((long)E + SC_EPB - 1) / SC_EPB);

        prep_kernel<<<pgrid_n, 256, 0, stream>>>(weight, wtb, nw, bcnt, NB,
                                                 (unsigned*)usedb, uw);
        bucket_scatter<<<cgrid, SC_THREADS, 0, stream>>>(dst, src, etypes, E, N, NB, STRIDE,
                                                         bcnt, items, usedb);
        dim3 pgrid((N + 127) / 128, 2);
        proj_all_kernel<<<pgrid, NTHREADS, 0, stream>>>(feat, wtb, usedb, N, R, projb);
        bucket_reduce<<<NB, 512, 0, stream>>>(bcnt, items, STRIDE, projb, N, out);
    } else {
        hipMemsetAsync(d_out, 0, (size_t)out_size * sizeof(float), stream);
        int mgrid = (E + TM - 1) / TM;
        rgcn_atomic<<<mgrid, NTHREADS, 0, stream>>>(feat, weight, src, dst, etypes, E, out);
    }
}

// Round 18
// 233.891 us; speedup vs baseline: 1.0204x; 1.0204x over previous
//
#include <hip/hip_runtime.h>
#include <hip/hip_bf16.h>

// RGCN gather-mm, etype-sorted edges.
// out[v][n] = sum_{e: dst[e]=v} sum_k feat[src[e]][k] * W[etype[e]][k][n]
//
// R29: consolidation = exact R27 (best measured, 235.0us). R28's scatter
// reshape (512thr/2048) regressed to 238.7 -> reverted to 1024thr/8192.
// Session asymptotes (all measured): proj 62-65us (latency floor of the
// barrier chain; traffic/wave/occupancy-invariant across R15-R25), scatter
// null under 2 shapes, reduce null under 3 shapes, launch boundary ~2us
// (R27), fusion/mega-kernel regress (R24/R26), LDS atomics never (R22).
// Chain: prep (zero bcnt+usedb, cvt W) -> bucket_scatter (fixed-stride,
// LDS-binned) -> proj (R25: grid.y=2 relation split, feat-once, LDS W
// dbuf, T14, lgkmcnt-only raw barriers, usedb-guarded sparse stores) ->
// bucket_reduce (R23: chunked LDS counting sort + register accumulate).
// Fallback: R4 atomic kernel (433us, known-good).

#define NTHREADS 256
#define TM 64
#define CH 2560          // bucket_reduce LDS chunk (items); avg bucket 2046

typedef __attribute__((ext_vector_type(8))) __bf16 bf16x8;
typedef __attribute__((ext_vector_type(4))) float f32x4;

// ---- prep: zero bcnt + usedb, cvt W [R][128][64] fp32 -> [R][64][128] bf16 ----
__global__ __launch_bounds__(256)
void prep_kernel(const float* __restrict__ w, __bf16* __restrict__ wtb, int nw,
                 int* __restrict__ bcnt, int NB,
                 unsigned* __restrict__ usedw, int uw) {
    long idx = (long)blockIdx.x * 256 + threadIdx.x;
    long tot = (long)NB + uw + nw;
    for (long i = idx; i < tot; i += (long)gridDim.x * 256) {
        if (i < NB) {
            bcnt[i] = 0;
        } else if (i < (long)NB + uw) {
            usedw[i - NB] = 0u;
        } else {
            int j = (int)(i - NB - uw);
            int r = j >> 13;
            int rem = j & 8191;
            int k = rem >> 6;
            int n = rem & 63;
            wtb[((size_t)r << 13) + (n << 7) + k] = (__bf16)w[j];
        }
    }
}

// ---- dense projection: HALF the relations per block (grid.y), LDS dbuf,
// ---- raw barriers, used-row-guarded stores (R25, proven 62.6us) ----
__global__ __launch_bounds__(NTHREADS)
void proj_all_kernel(const float* __restrict__ feat, const __bf16* __restrict__ wtb,
                     const unsigned char* __restrict__ usedb,
                     int N, int R, __bf16* __restrict__ projb) {
    __shared__ __bf16 Wt[2][64 * 136];
    __shared__ unsigned used_l[16 * 32];   // rpb<=16 x 128 bytes, as u32

    int t = threadIdx.x;
    int wave = t >> 6, lane = t & 63;
    int q = lane >> 4, m = lane & 15;
    long blk0 = (long)blockIdx.x * 128;
    long node0 = blk0 + wave * 32;

    int rpb = (R + 1) >> 1;                 // relations per block
    int r0 = blockIdx.y * rpb;
    int r1 = r0 + rpb; if (r1 > R) r1 = R;
    int nr = r1 - r0;
    if (nr <= 0) return;

    // preload used bytes for this block's 128 nodes x [r0,r1) relations
    for (int c = t; c < nr * 32; c += NTHREADS) {
        int rr = c >> 5, i = c & 31;
        used_l[rr * 32 + i] = *(const unsigned*)(usedb + (size_t)(r0 + rr) * N + blk0 + i * 4);
    }

    // A fragments: fp32 feat -> bf16, loaded once for this block's relations.
    bf16x8 a[2][4];
    #pragma unroll
    for (int mt = 0; mt < 2; mt++) {
        long nd = node0 + mt * 16 + m;
        if (nd > N - 1) nd = N - 1;
        const float* arow = feat + nd * 128;
        #pragma unroll
        for (int ks = 0; ks < 4; ks++) {
            float4 fa = *(const float4*)(arow + ks * 32 + q * 8);
            float4 fb = *(const float4*)(arow + ks * 32 + q * 8 + 4);
            bf16x8 v;
            v[0] = (__bf16)fa.x; v[1] = (__bf16)fa.y; v[2] = (__bf16)fa.z; v[3] = (__bf16)fa.w;
            v[4] = (__bf16)fb.x; v[5] = (__bf16)fb.y; v[6] = (__bf16)fb.z; v[7] = (__bf16)fb.w;
            a[mt][ks] = v;
        }
    }

    // stage r=r0 into buffer 0
    {
        const __bf16* wg = wtb + ((size_t)r0 << 13);
        #pragma unroll
        for (int i = 0; i < 4; i++) {
            int c = t + i * 256;
            int n = c >> 4, kc = c & 15;
            *(bf16x8*)(&Wt[0][n * 136 + kc * 8]) = *(const bf16x8*)(wg + n * 128 + kc * 8);
        }
    }
    asm volatile("s_waitcnt lgkmcnt(0)" ::: "memory");
    __builtin_amdgcn_s_barrier();
    __builtin_amdgcn_sched_barrier(0);

    for (int ri = 0; ri < nr; ri++) {
        int r = r0 + ri;
        int cur = ri & 1, nxt = cur ^ 1;
        bool pf = (ri + 1 < nr);

        // T14 async-STAGE: issue next-relation W loads now; write to LDS late.
        bf16x8 wreg[4];
        if (pf) {
            const __bf16* wg = wtb + ((size_t)(r + 1) << 13);
            #pragma unroll
            for (int i = 0; i < 4; i++) {
                int c = t + i * 256;
                int n = c >> 4, kc = c & 15;
                wreg[i] = *(const bf16x8*)(wg + n * 128 + kc * 8);
            }
        }

        f32x4 acc[2][4] = {};
        #pragma unroll
        for (int ks = 0; ks < 4; ks++) {
            bf16x8 b0 = *(const bf16x8*)(&Wt[cur][(0 * 16 + m) * 136 + ks * 32 + q * 8]);
            bf16x8 b1 = *(const bf16x8*)(&Wt[cur][(1 * 16 + m) * 136 + ks * 32 + q * 8]);
            bf16x8 b2 = *(const bf16x8*)(&Wt[cur][(2 * 16 + m) * 136 + ks * 32 + q * 8]);
            bf16x8 b3 = *(const bf16x8*)(&Wt[cur][(3 * 16 + m) * 136 + ks * 32 + q * 8]);
            #pragma unroll
            for (int mt = 0; mt < 2; mt++) {
                acc[mt][0] = __builtin_amdgcn_mfma_f32_16x16x32_bf16(a[mt][ks], b0, acc[mt][0], 0, 0, 0);
                acc[mt][1] = __builtin_amdgcn_mfma_f32_16x16x32_bf16(a[mt][ks], b1, acc[mt][1], 0, 0, 0);
                acc[mt][2] = __builtin_amdgcn_mfma_f32_16x16x32_bf16(a[mt][ks], b2, acc[mt][2], 0, 0, 0);
                acc[mt][3] = __builtin_amdgcn_mfma_f32_16x16x32_bf16(a[mt][ks], b3, acc[mt][3], 0, 0, 0);
            }
        }

        // C/D: col = nt*16+m, node = mt*16+q*4+reg. Permuted c' = m*4+nt.
        // Store only rows some edge will read (usedb guard).
        #pragma unroll
        for (int mt = 0; mt < 2; mt++) {
            unsigned g = used_l[ri * 32 + ((wave * 32 + mt * 16 + q * 4) >> 2)];
            #pragma unroll
            for (int reg = 0; reg < 4; reg++) {
                long nd = node0 + mt * 16 + q * 4 + reg;
                if (nd < N && ((g >> (reg * 8)) & 1)) {
                    union { unsigned long long u; __bf16 h[4]; } pk;
                    pk.h[0] = (__bf16)acc[mt][0][reg];
                    pk.h[1] = (__bf16)acc[mt][1][reg];
                    pk.h[2] = (__bf16)acc[mt][2][reg];
                    pk.h[3] = (__bf16)acc[mt][3][reg];
                    *(unsigned long long*)(projb + ((size_t)r * N + nd) * 64 + m * 4) = pk.u;
                }
            }
        }

        if (pf) {
            #pragma unroll
            for (int i = 0; i < 4; i++) {
                int c = t + i * 256;
                int n = c >> 4, kc = c & 15;
                *(bf16x8*)(&Wt[nxt][n * 136 + kc * 8]) = wreg[i];
            }
            asm volatile("s_waitcnt lgkmcnt(0)" ::: "memory");
            __builtin_amdgcn_s_barrier();
            __builtin_amdgcn_sched_barrier(0);
        }
    }
}

// ---- LDS-binned scatter into FIXED-STRIDE buckets (R22/R23/R27, proven) ----
// item = (dst&127)<<24 | (etype*N + src)   [R*N < 2^24 guarded]
// Reserves per-bucket slots via atomicAdd(bcnt) -- no hist/scan needed.
// Also marks usedb[etype*N+src] (idempotent byte store) for proj's guard.
__global__ __launch_bounds__(1024)
void bucket_scatter(const int* __restrict__ dst, const int* __restrict__ src,
                    const int* __restrict__ etypes, int E, int N, int NB, int STRIDE,
                    int* __restrict__ bcnt, int* __restrict__ items,
                    unsigned char* __restrict__ usedb) {
    __shared__ int lh[1024], lb[1024];
    int t = threadIdx.x;
    lh[t] = 0;
    __syncthreads();
    long base = (long)blockIdx.x * 8192;
    int bs[8], it[8];
    #pragma unroll
    for (int i = 0; i < 8; i++) {
        long e = base + t + 1024 * i;
        if (e < E) {
            int d = dst[e];
            int bkt = d >> 7;
            bs[i] = bkt;
            int pair = etypes[e] * N + src[e];
            it[i] = ((d & 127) << 24) | pair;
            usedb[pair] = 1;
            atomicAdd(&lh[bkt], 1);
        } else bs[i] = -1;
    }
    __syncthreads();
    for (int bb = t; bb < NB; bb += 1024) {
        int c = lh[bb];
        lb[bb] = c ? atomicAdd(&bcnt[bb], c) : 0;
        lh[bb] = 0;
    }
    __syncthreads();
    #pragma unroll
    for (int i = 0; i < 8; i++) {
        if (bs[i] >= 0) {
            int pos = lb[bs[i]] + atomicAdd(&lh[bs[i]], 1);
            if (pos < STRIDE)
                items[(size_t)bs[i] * STRIDE + pos] = it[i];
        }
    }
}

// ---- fused sort+reduce per bucket (R21/R23 core, fixed-stride input) ----
// Chunked LDS counting sort of the bucket's 24-bit pairs, then gather-
// reduce from LDS: 64 8-lane subs, sub handles dsts {sub, sub+64} with
// register acc; lane c8 owns permuted cols c8*8..c8*8+7 (16B/row gather).
__global__ __launch_bounds__(512)
void bucket_reduce(const int* __restrict__ bcnt, const int* __restrict__ items,
                   int STRIDE, const __bf16* __restrict__ projb, int N,
                   float* __restrict__ out) {
    __shared__ int h[128], sc[128], cur[128];
    __shared__ int its[CH];
    int b = blockIdx.x, t = threadIdx.x;
    int cnt = bcnt[b]; if (cnt > STRIDE) cnt = STRIDE;
    const int* bitems = items + (size_t)b * STRIDE;
    int sub = t >> 3, c8 = t & 7;

    float acc[2][8] = {};

    for (int c0 = 0; c0 < cnt; c0 += CH) {
        int n = cnt - c0; if (n > CH) n = CH;

        if (t < 128) h[t] = 0;
        __syncthreads();

        int my[CH / 512];
        int dl[CH / 512];
        #pragma unroll
        for (int i = 0; i < CH / 512; i++) {
            int k = t + i * 512;
            if (k < n) {
                my[i] = bitems[c0 + k];
                dl[i] = ((unsigned)my[i]) >> 24;
                atomicAdd(&h[dl[i]], 1);
            } else dl[i] = -1;
        }
        __syncthreads();

        if (t < 128) sc[t] = h[t];
        __syncthreads();
        for (int s = 1; s < 128; s <<= 1) {        // inclusive scan
            int add = (t >= s && t < 128) ? sc[t - s] : 0;
            __syncthreads();
            if (t < 128) sc[t] += add;
            __syncthreads();
        }
        if (t < 128) cur[t] = sc[t] - h[t];        // exclusive
        __syncthreads();

        #pragma unroll
        for (int i = 0; i < CH / 512; i++) {
            if (dl[i] >= 0) {
                int pos = atomicAdd(&cur[dl[i]], 1);
                its[pos] = my[i] & 0xFFFFFF;
            }
        }
        __syncthreads();

        // gather-reduce this chunk's sorted runs
        #pragma unroll
        for (int idx = 0; idx < 2; idx++) {
            int d = sub + idx * 64;
            int s = sc[d] - h[d];
            int e = sc[d];
            int k = s;
            for (; k + 1 < e; k += 2) {
                int p0 = its[k], p1 = its[k + 1];
                bf16x8 v0 = *(const bf16x8*)(projb + (size_t)p0 * 64 + c8 * 8);
                bf16x8 v1 = *(const bf16x8*)(projb + (size_t)p1 * 64 + c8 * 8);
                #pragma unroll
                for (int i = 0; i < 8; i++) acc[idx][i] += (float)v0[i] + (float)v1[i];
            }
            if (k < e) {
                int p = its[k];
                bf16x8 v0 = *(const bf16x8*)(projb + (size_t)p * 64 + c8 * 8);
                #pragma unroll
                for (int i = 0; i < 8; i++) acc[idx][i] += (float)v0[i];
            }
        }
        __syncthreads();   // its/h/sc reused next chunk
    }

    // store: v = b*128 + d, lane owns permuted cols c8*8..+7
    #pragma unroll
    for (int idx = 0; idx < 2; idx++) {
        long v = (long)b * 128 + sub + idx * 64;
        if (v < N) {
            float* orow = out + (size_t)v * 64;
            #pragma unroll
            for (int i = 0; i < 8; i++) {
                int cp = c8 * 8 + i;
                orow[(cp & 3) * 16 + (cp >> 2)] = acc[idx][i];
            }
        }
    }
}

// ---- fallback: atomic scatter (R4, known-good 433us; no ws use) ----
__global__ __launch_bounds__(NTHREADS)
void rgcn_atomic(const float* __restrict__ feat, const float* __restrict__ weight,
                 const int* __restrict__ src, const int* __restrict__ dst,
                 const int* __restrict__ etypes, int E,
                 float* __restrict__ out) {
    __shared__ __bf16 Wt[64 * 136];
    int b = blockIdx.x;
    int e0 = b * TM;
    int t = threadIdx.x;
    int wave = t >> 6, lane = t & 63;
    int q = lane >> 4, m = lane & 15;
    int wbase = e0 + wave * 16;
    int last = e0 + TM - 1; if (last > E - 1) last = E - 1;
    int rmin = etypes[e0];
    int rmax = etypes[last];
    int em = wbase + m;
    bool rowok = em < E;
    int ei = rowok ? em : E - 1;
    int my_et = rowok ? etypes[em] : -1;
    const float* arow = feat + (long)src[ei] * 128;
    bf16x8 a[4];
    #pragma unroll
    for (int ks = 0; ks < 4; ks++) {
        float4 fa = *(const float4*)(arow + ks * 32 + q * 8);
        float4 fb = *(const float4*)(arow + ks * 32 + q * 8 + 4);
        bf16x8 v;
        v[0] = (__bf16)fa.x; v[1] = (__bf16)fa.y;
        v[2] = (__bf16)fa.z; v[3] = (__bf16)fa.w;
        v[4] = (__bf16)fb.x; v[5] = (__bf16)fb.y;
        v[6] = (__bf16)fb.z; v[7] = (__bf16)fb.w;
        a[ks] = v;
    }
    f32x4 acc0 = {0.f, 0.f, 0.f, 0.f};
    f32x4 acc1 = {0.f, 0.f, 0.f, 0.f};
    f32x4 acc2 = {0.f, 0.f, 0.f, 0.f};
    f32x4 acc3 = {0.f, 0.f, 0.f, 0.f};
    for (int r = rmin; r <= rmax; ++r) {
        if (r != rmin) __syncthreads();
        const float* wg = weight + (r << 13);
        for (int p = t; p < 4096; p += NTHREADS) {
            int n = p & 63, kh = p >> 6;
            float w0 = wg[(kh * 2) * 64 + n];
            float w1 = wg[(kh * 2 + 1) * 64 + n];
            union { unsigned u; __bf16 h[2]; } pk;
            pk.h[0] = (__bf16)w0; pk.h[1] = (__bf16)w1;
            *(unsigned*)&Wt[n * 136 + kh * 2] = pk.u;
        }
        __syncthreads();
        bool on = (my_et == r);
        #pragma unroll
        for (int ks = 0; ks < 4; ks++) {
            bf16x8 af = a[ks];
            if (!on) {
                #pragma unroll
                for (int j = 0; j < 8; j++) af[j] = (__bf16)0.f;
            }
            bf16x8 b0 = *(const bf16x8*)(&Wt[(0 * 16 + m) * 136 + ks * 32 + q * 8]);
            bf16x8 b1 = *(const bf16x8*)(&Wt[(1 * 16 + m) * 136 + ks * 32 + q * 8]);
            bf16x8 b2 = *(const bf16x8*)(&Wt[(2 * 16 + m) * 136 + ks * 32 + q * 8]);
            bf16x8 b3 = *(const bf16x8*)(&Wt[(3 * 16 + m) * 136 + ks * 32 + q * 8]);
            acc0 = __builtin_amdgcn_mfma_f32_16x16x32_bf16(af, b0, acc0, 0, 0, 0);
            acc1 = __builtin_amdgcn_mfma_f32_16x16x32_bf16(af, b1, acc1, 0, 0, 0);
            acc2 = __builtin_amdgcn_mfma_f32_16x16x32_bf16(af, b2, acc2, 0, 0, 0);
            acc3 = __builtin_amdgcn_mfma_f32_16x16x32_bf16(af, b3, acc3, 0, 0, 0);
        }
    }
    #pragma unroll
    for (int reg = 0; reg < 4; reg++) {
        int er = wbase + q * 4 + reg;
        if (er < E) {
            float* orow = out + (long)dst[er] * 64;
            unsafeAtomicAdd(orow + 0 * 16 + m, acc0[reg]);
            unsafeAtomicAdd(orow + 1 * 16 + m, acc1[reg]);
            unsafeAtomicAdd(orow + 2 * 16 + m, acc2[reg]);
            unsafeAtomicAdd(orow + 3 * 16 + m, acc3[reg]);
        }
    }
}

extern "C" void kernel_launch(void* const* d_in, const int* in_sizes, int n_in,
                              void* d_out, int out_size, void* d_ws, size_t ws_size,
                              hipStream_t stream) {
    const float* feat   = (const float*)d_in[0];
    const float* weight = (const float*)d_in[1];
    const int*   src    = (const int*)d_in[2];
    const int*   dst    = (const int*)d_in[3];
    const int*   etypes = (const int*)d_in[4];
    float* out = (float*)d_out;

    int nfeat = in_sizes[0];
    int nw    = in_sizes[1];
    int E     = in_sizes[2];
    int N     = nfeat / 128;
    int R     = nw >> 13;
    int NB    = (N + 127) >> 7;      // buckets of 128 dsts

    // fixed bucket stride: 2x average, 64-aligned, >=1024
    int avg = (int)(((long)E + NB - 1) / NB);
    int STRIDE = ((avg * 2 + 63) / 64) * 64;
    if (STRIDE < 1024) STRIDE = 1024;

    // ws layout (256B-aligned slabs)
    size_t o = 0;
    auto take = [&](size_t bytes) { size_t r = o; o = (o + bytes + 255) & ~(size_t)255; return r; };
    size_t o_bcnt  = take((size_t)NB * 4);
    size_t o_usedb = take((size_t)R * N);          // used (r,src) byte map
    size_t o_items = take((size_t)NB * STRIDE * 4);
    size_t o_wtb   = take((size_t)nw * 2);
    size_t o_projb = take((size_t)R * N * 64 * 2);
    size_t need = o;

    bool fast = (ws_size >= need) && (NB <= 1024) && ((size_t)R * N < (1u << 24))
                && (R <= 16) && ((N & 3) == 0);

    if (fast) {
        char* ws = (char*)d_ws;
        int* bcnt  = (int*)(ws + o_bcnt);
        unsigned char* usedb = (unsigned char*)(ws + o_usedb);
        int* items = (int*)(ws + o_items);
        __bf16* wtb   = (__bf16*)(ws + o_wtb);
        __bf16* projb = (__bf16*)(ws + o_projb);

        int uw = (int)(((size_t)R * N + 3) >> 2);      // usedb words (slab padded)
        long ptot = (long)NB + uw + nw;
        int pgrid_n = (int)((ptot + 255) / 256);
        if (pgrid_n > 2048) pgrid_n = 2048;            // grid-stride caps the rest

        int cgrid = (int)(((long)E + 8191) / 8192);

        prep_kernel<<<pgrid_n, 256, 0, stream>>>(weight, wtb, nw, bcnt, NB,
                                                 (unsigned*)usedb, uw);
        bucket_scatter<<<cgrid, 1024, 0, stream>>>(dst, src, etypes, E, N, NB, STRIDE,
                                                   bcnt, items, usedb);
        dim3 pgrid((N + 127) / 128, 2);
        proj_all_kernel<<<pgrid, NTHREADS, 0, stream>>>(feat, wtb, usedb, N, R, projb);
        bucket_reduce<<<NB, 512, 0, stream>>>(bcnt, items, STRIDE, projb, N, out);
    } else {
        hipMemsetAsync(d_out, 0, (size_t)out_size * sizeof(float), stream);
        int mgrid = (E + TM - 1) / TM;
        rgcn_atomic<<<mgrid, NTHREADS, 0, stream>>>(feat, weight, src, dst, etypes, E, out);
    }
}